// Round 2
// baseline (1227.587 us; speedup 1.0000x reference)
//
#include <hip/hip_runtime.h>
#include <stdint.h>

#define NTOK 524288
#define ROWS 64
#define CHUNKS 64
#define NTHR 256
#define F4_PER_ROW (NTOK / 4)                 // 131072
#define F4_PER_CHUNK (F4_PER_ROW / CHUNKS)    // 2048
#define F4_PER_THR (F4_PER_CHUNK / NTHR)      // 8
#define GCAP 8192

// ---- workspace layout (bytes) ----
#define OFF_H1   0u
#define OFF_H2   (OFF_H1 + ROWS * 4096u * 4u)          // 1 MiB
#define OFF_B1   (OFF_H2 + ROWS * 4096u * 4u)          // 2 MiB
#define OFF_CG   (OFF_B1 + ROWS * 4u)
#define OFF_B2   (OFF_CG + ROWS * 4u)
#define OFF_REM  (OFF_B2 + ROWS * 4u)
#define OFF_IT   (OFF_REM + ROWS * 4u)
#define OFF_GCNT (OFF_IT + ROWS * 4u)
#define OFF_T    (OFF_GCNT + ROWS * 4u)                // 8-aligned
#define OFF_ZERO_END (OFF_T + ROWS * 8u)
#define OFF_TAB  OFF_ZERO_END                          // 64*112 doubles
#define OFF_GKEY (OFF_TAB + ROWS * 112u * 8u)
#define OFF_GIDX (OFF_GKEY + ROWS * (unsigned)GCAP * 8u)
#define WS_NEED  (OFF_GIDX + ROWS * (unsigned)GCAP * 4u)

__device__ __forceinline__ double clamp64(double x) {
  return fmin(fmax(x, 1.0e-3), 1.0 - 1.0e-3);
}

// ---- precompute per-row dim factor tables: F = clamp(u)^(1/alpha), f64 ----
__global__ void k_tables(const float* __restrict__ comps, const int* __restrict__ idxp,
                         const float* __restrict__ uvs, const float* __restrict__ uts,
                         const float* __restrict__ uhs, const float* __restrict__ uws,
                         const float* __restrict__ uvt, const float* __restrict__ utt,
                         const float* __restrict__ uht, const float* __restrict__ uwt,
                         double* __restrict__ tabs) {
  int idx = idxp[0];
  double alpha[4];
  for (int d = 0; d < 4; ++d) alpha[d] = (double)comps[idx * 4 + d];
  for (int i = threadIdx.x; i < ROWS * 112; i += blockDim.x) {
    int row = i / 112, j = i % 112;
    int m = row >> 5, b = row & 31;
    int d, jj, dsz;
    if (j < 16)      { d = 0; jj = j;      dsz = 16; }
    else if (j < 48) { d = 1; jj = j - 16; dsz = 32; }
    else if (j < 80) { d = 2; jj = j - 48; dsz = 32; }
    else             { d = 3; jj = j - 80; dsz = 32; }
    const float* u;
    if (m == 0) u = (d == 0) ? uvs : (d == 1) ? uts : (d == 2) ? uhs : uws;
    else        u = (d == 0) ? uvt : (d == 1) ? utt : (d == 2) ? uht : uwt;
    double x = clamp64((double)u[b * dsz + jj]);
    double a = alpha[d];
    double f;
    if (a == 1.0)      f = x;
    else if (a == 2.0) f = sqrt(x);
    else if (a == 4.0) f = sqrt(sqrt(x));
    else               f = pow(x, 1.0 / a);
    tabs[row * 112 + j] = f;
  }
}

// ---- K exactly as reference: float32 clamp, float32 multiply, truncate ----
__device__ __forceinline__ unsigned compute_K(float ur) {
  float urf = fminf(fmaxf(ur, 1.0e-3f), 1.0f - 1.0e-3f);
  return (unsigned)(int)(urf * (float)NTOK);
}

// ---- pass 1: 12-bit histogram of key bits [62:51] ----
__global__ void k_hist1(const float* __restrict__ u0s, const float* __restrict__ u0t,
                        const double* __restrict__ tabs, unsigned int* __restrict__ gh1) {
  __shared__ double tb[112];
  __shared__ unsigned int h[4096];
  int row = blockIdx.x / CHUNKS, chunk = blockIdx.x % CHUNKS;
  for (int i = threadIdx.x; i < 112; i += blockDim.x) tb[i] = tabs[row * 112 + i];
  for (int i = threadIdx.x; i < 4096; i += blockDim.x) h[i] = 0;
  __syncthreads();
  int m = row >> 5, b = row & 31;
  const float4* u0 = reinterpret_cast<const float4*>((m ? u0t : u0s) + (size_t)b * NTOK);
  int base = chunk * F4_PER_CHUNK;
  for (int it = 0; it < F4_PER_THR; ++it) {
    int f4 = base + it * NTHR + threadIdx.x;
    float4 x = u0[f4];
    int n0 = f4 * 4;
    int w0 = n0 & 31, hh = (n0 >> 5) & 31, tt = (n0 >> 10) & 31, vv = n0 >> 15;
    double g = tb[vv] * tb[16 + tt] * tb[48 + hh];
    double k0 = clamp64((double)x.x) * (g * tb[80 + w0 + 0]);
    double k1 = clamp64((double)x.y) * (g * tb[80 + w0 + 1]);
    double k2 = clamp64((double)x.z) * (g * tb[80 + w0 + 2]);
    double k3 = clamp64((double)x.w) * (g * tb[80 + w0 + 3]);
    atomicAdd(&h[(unsigned)((unsigned long long)__double_as_longlong(k0) >> 51) & 0xFFFu], 1u);
    atomicAdd(&h[(unsigned)((unsigned long long)__double_as_longlong(k1) >> 51) & 0xFFFu], 1u);
    atomicAdd(&h[(unsigned)((unsigned long long)__double_as_longlong(k2) >> 51) & 0xFFFu], 1u);
    atomicAdd(&h[(unsigned)((unsigned long long)__double_as_longlong(k3) >> 51) & 0xFFFu], 1u);
  }
  __syncthreads();
  for (int i = threadIdx.x; i < 4096; i += blockDim.x) {
    unsigned c = h[i];
    if (c) atomicAdd(&gh1[row * 4096 + i], c);
  }
}

// ---- scan 1: find bucket B1 containing the K-th largest ----
__global__ void k_scan1(const unsigned int* __restrict__ gh1,
                        const float* __restrict__ urs, const float* __restrict__ urt,
                        int* __restrict__ sB1, int* __restrict__ sCG) {
  int row = threadIdx.x;
  if (row >= ROWS) return;
  int m = row >> 5;
  unsigned K = compute_K(m ? urt[0] : urs[0]);
  unsigned cum = 0; int b1 = 0; unsigned cg = 0;
  for (int b = 4095; b >= 0; --b) {
    unsigned c = gh1[row * 4096 + b];
    if (cum + c >= K) { b1 = b; cg = cum; break; }
    cum += c;
  }
  sB1[row] = b1;
  sCG[row] = (int)cg;
}

// ---- pass 2: refine bits [50:39] within bucket B1 ----
__global__ void k_hist2(const float* __restrict__ u0s, const float* __restrict__ u0t,
                        const double* __restrict__ tabs, const int* __restrict__ sB1,
                        unsigned int* __restrict__ gh2) {
  __shared__ double tb[112];
  __shared__ unsigned int h[4096];
  int row = blockIdx.x / CHUNKS, chunk = blockIdx.x % CHUNKS;
  for (int i = threadIdx.x; i < 112; i += blockDim.x) tb[i] = tabs[row * 112 + i];
  for (int i = threadIdx.x; i < 4096; i += blockDim.x) h[i] = 0;
  __syncthreads();
  unsigned b1 = (unsigned)sB1[row];
  int m = row >> 5, b = row & 31;
  const float4* u0 = reinterpret_cast<const float4*>((m ? u0t : u0s) + (size_t)b * NTOK);
  int base = chunk * F4_PER_CHUNK;
  for (int it = 0; it < F4_PER_THR; ++it) {
    int f4 = base + it * NTHR + threadIdx.x;
    float4 x = u0[f4];
    int n0 = f4 * 4;
    int w0 = n0 & 31, hh = (n0 >> 5) & 31, tt = (n0 >> 10) & 31, vv = n0 >> 15;
    double g = tb[vv] * tb[16 + tt] * tb[48 + hh];
    double ks[4];
    ks[0] = clamp64((double)x.x) * (g * tb[80 + w0 + 0]);
    ks[1] = clamp64((double)x.y) * (g * tb[80 + w0 + 1]);
    ks[2] = clamp64((double)x.z) * (g * tb[80 + w0 + 2]);
    ks[3] = clamp64((double)x.w) * (g * tb[80 + w0 + 3]);
#pragma unroll
    for (int c = 0; c < 4; ++c) {
      unsigned long long kb = (unsigned long long)__double_as_longlong(ks[c]);
      if (((unsigned)(kb >> 51) & 0xFFFu) == b1)
        atomicAdd(&h[(unsigned)(kb >> 39) & 0xFFFu], 1u);
    }
  }
  __syncthreads();
  for (int i = threadIdx.x; i < 4096; i += blockDim.x) {
    unsigned c = h[i];
    if (c) atomicAdd(&gh2[row * 4096 + i], c);
  }
}

// ---- scan 2: find bucket B2, remaining count ----
__global__ void k_scan2(const unsigned int* __restrict__ gh2,
                        const float* __restrict__ urs, const float* __restrict__ urt,
                        const int* __restrict__ sCG,
                        int* __restrict__ sB2, int* __restrict__ sREM) {
  int row = threadIdx.x;
  if (row >= ROWS) return;
  int m = row >> 5;
  unsigned K = compute_K(m ? urt[0] : urs[0]);
  unsigned cum = (unsigned)sCG[row];
  int b2 = 0; unsigned rem = 1;
  for (int b = 4095; b >= 0; --b) {
    unsigned c = gh2[row * 4096 + b];
    if (cum + c >= K) { b2 = b; rem = K - cum; break; }
    cum += c;
  }
  sB2[row] = b2;
  sREM[row] = (int)rem;
}

// ---- pass 3: gather all elements matching the 24-bit prefix ----
__global__ void k_gather(const float* __restrict__ u0s, const float* __restrict__ u0t,
                         const double* __restrict__ tabs,
                         const int* __restrict__ sB1, const int* __restrict__ sB2,
                         unsigned int* __restrict__ gcnt,
                         unsigned long long* __restrict__ gkey, unsigned int* __restrict__ gidx) {
  __shared__ double tb[112];
  int row = blockIdx.x / CHUNKS, chunk = blockIdx.x % CHUNKS;
  for (int i = threadIdx.x; i < 112; i += blockDim.x) tb[i] = tabs[row * 112 + i];
  __syncthreads();
  unsigned pref = ((unsigned)sB1[row] << 12) | (unsigned)sB2[row];
  int m = row >> 5, b = row & 31;
  const float4* u0 = reinterpret_cast<const float4*>((m ? u0t : u0s) + (size_t)b * NTOK);
  int base = chunk * F4_PER_CHUNK;
  for (int it = 0; it < F4_PER_THR; ++it) {
    int f4 = base + it * NTHR + threadIdx.x;
    float4 x = u0[f4];
    int n0 = f4 * 4;
    int w0 = n0 & 31, hh = (n0 >> 5) & 31, tt = (n0 >> 10) & 31, vv = n0 >> 15;
    double g = tb[vv] * tb[16 + tt] * tb[48 + hh];
    double ks[4];
    ks[0] = clamp64((double)x.x) * (g * tb[80 + w0 + 0]);
    ks[1] = clamp64((double)x.y) * (g * tb[80 + w0 + 1]);
    ks[2] = clamp64((double)x.z) * (g * tb[80 + w0 + 2]);
    ks[3] = clamp64((double)x.w) * (g * tb[80 + w0 + 3]);
#pragma unroll
    for (int c = 0; c < 4; ++c) {
      unsigned long long kb = (unsigned long long)__double_as_longlong(ks[c]);
      if (((unsigned)(kb >> 39) & 0xFFFFFFu) == pref) {
        unsigned pos = atomicAdd(&gcnt[row], 1u);
        if (pos < GCAP) {
          gkey[(size_t)row * GCAP + pos] = kb;
          gidx[(size_t)row * GCAP + pos] = (unsigned)(n0 + c);
        }
      }
    }
  }
}

// ---- pass 4: one block per row, bitonic sort (key desc, idx asc), pick rem-th ----
__global__ __launch_bounds__(1024) void k_select(const unsigned long long* __restrict__ gkey,
                                                 const unsigned int* __restrict__ gidx,
                                                 const unsigned int* __restrict__ gcnt,
                                                 const int* __restrict__ sREM,
                                                 unsigned long long* __restrict__ sT,
                                                 int* __restrict__ sIT) {
  __shared__ unsigned long long k[GCAP];
  __shared__ unsigned int ix[GCAP];
  int row = blockIdx.x;
  unsigned n_r = gcnt[row];
  if (n_r > GCAP) n_r = GCAP;
  for (int i = threadIdx.x; i < GCAP; i += blockDim.x) {
    if ((unsigned)i < n_r) { k[i] = gkey[(size_t)row * GCAP + i]; ix[i] = gidx[(size_t)row * GCAP + i]; }
    else                   { k[i] = 0ULL; ix[i] = 0xFFFFFFFFu; }
  }
  __syncthreads();
  for (int kk = 2; kk <= GCAP; kk <<= 1) {
    for (int j = kk >> 1; j > 0; j >>= 1) {
      for (int i = threadIdx.x; i < GCAP; i += blockDim.x) {
        int pj = i ^ j;
        if (pj > i) {
          unsigned long long k1 = k[i], k2 = k[pj];
          unsigned i1 = ix[i], i2 = ix[pj];
          bool bef = (k1 > k2) || (k1 == k2 && i1 < i2);  // i's element should precede
          bool dirAsc = ((i & kk) == 0);
          if (bef != dirAsc) { k[i] = k2; k[pj] = k1; ix[i] = i2; ix[pj] = i1; }
        }
      }
      __syncthreads();
    }
  }
  if (threadIdx.x == 0) {
    int rem = sREM[row];
    if (rem < 1) rem = 1;
    if ((unsigned)rem > n_r) rem = (int)n_r;
    sT[row] = k[rem - 1];
    sIT[row] = (int)ix[rem - 1];
  }
}

// ---- pass 5: write masks as int32 0/1 (harness reads d_out as int32) ----
__global__ void k_final(const float* __restrict__ u0s, const float* __restrict__ u0t,
                        const double* __restrict__ tabs,
                        const unsigned long long* __restrict__ sT, const int* __restrict__ sIT,
                        int* __restrict__ out) {
  __shared__ double tb[112];
  int row = blockIdx.x / CHUNKS, chunk = blockIdx.x % CHUNKS;
  for (int i = threadIdx.x; i < 112; i += blockDim.x) tb[i] = tabs[row * 112 + i];
  __syncthreads();
  unsigned long long T = sT[row];
  int IT = sIT[row];
  int m = row >> 5, b = row & 31;
  const float4* u0 = reinterpret_cast<const float4*>((m ? u0t : u0s) + (size_t)b * NTOK);
  int4* o = reinterpret_cast<int4*>(out + (size_t)row * NTOK);
  int base = chunk * F4_PER_CHUNK;
  for (int it = 0; it < F4_PER_THR; ++it) {
    int f4 = base + it * NTHR + threadIdx.x;
    float4 x = u0[f4];
    int n0 = f4 * 4;
    int w0 = n0 & 31, hh = (n0 >> 5) & 31, tt = (n0 >> 10) & 31, vv = n0 >> 15;
    double g = tb[vv] * tb[16 + tt] * tb[48 + hh];
    unsigned long long kb0 = (unsigned long long)__double_as_longlong(clamp64((double)x.x) * (g * tb[80 + w0 + 0]));
    unsigned long long kb1 = (unsigned long long)__double_as_longlong(clamp64((double)x.y) * (g * tb[80 + w0 + 1]));
    unsigned long long kb2 = (unsigned long long)__double_as_longlong(clamp64((double)x.z) * (g * tb[80 + w0 + 2]));
    unsigned long long kb3 = (unsigned long long)__double_as_longlong(clamp64((double)x.w) * (g * tb[80 + w0 + 3]));
    int4 r;
    r.x = (kb0 > T || (kb0 == T && (n0 + 0) <= IT)) ? 1 : 0;
    r.y = (kb1 > T || (kb1 == T && (n0 + 1) <= IT)) ? 1 : 0;
    r.z = (kb2 > T || (kb2 == T && (n0 + 2) <= IT)) ? 1 : 0;
    r.w = (kb3 > T || (kb3 == T && (n0 + 3) <= IT)) ? 1 : 0;
    o[f4] = r;
  }
}

extern "C" void kernel_launch(void* const* d_in, const int* in_sizes, int n_in,
                              void* d_out, int out_size, void* d_ws, size_t ws_size,
                              hipStream_t stream) {
  const float* comps = (const float*)d_in[0];
  const float* urs   = (const float*)d_in[1];
  const float* urt   = (const float*)d_in[2];
  const float* u0s   = (const float*)d_in[3];
  const float* u0t   = (const float*)d_in[4];
  const float* uvs   = (const float*)d_in[5];
  const float* uts   = (const float*)d_in[6];
  const float* uhs   = (const float*)d_in[7];
  const float* uws   = (const float*)d_in[8];
  const float* uvt   = (const float*)d_in[9];
  const float* utt   = (const float*)d_in[10];
  const float* uht   = (const float*)d_in[11];
  const float* uwt   = (const float*)d_in[12];
  const int*   idxp  = (const int*)d_in[13];
  int* out = (int*)d_out;

  char* ws = (char*)d_ws;
  unsigned int*       gh1  = (unsigned int*)(ws + OFF_H1);
  unsigned int*       gh2  = (unsigned int*)(ws + OFF_H2);
  int*                sB1  = (int*)(ws + OFF_B1);
  int*                sCG  = (int*)(ws + OFF_CG);
  int*                sB2  = (int*)(ws + OFF_B2);
  int*                sREM = (int*)(ws + OFF_REM);
  int*                sIT  = (int*)(ws + OFF_IT);
  unsigned int*       gcnt = (unsigned int*)(ws + OFF_GCNT);
  unsigned long long* sT   = (unsigned long long*)(ws + OFF_T);
  double*             tabs = (double*)(ws + OFF_TAB);
  unsigned long long* gkey = (unsigned long long*)(ws + OFF_GKEY);
  unsigned int*       gidx = (unsigned int*)(ws + OFF_GIDX);

  // zero hists + state + counters (ws is poisoned 0xAA before every call)
  hipMemsetAsync(d_ws, 0, OFF_ZERO_END, stream);

  k_tables<<<1, 256, 0, stream>>>(comps, idxp, uvs, uts, uhs, uws, uvt, utt, uht, uwt, tabs);
  k_hist1<<<ROWS * CHUNKS, NTHR, 0, stream>>>(u0s, u0t, tabs, gh1);
  k_scan1<<<1, 64, 0, stream>>>(gh1, urs, urt, sB1, sCG);
  k_hist2<<<ROWS * CHUNKS, NTHR, 0, stream>>>(u0s, u0t, tabs, sB1, gh2);
  k_scan2<<<1, 64, 0, stream>>>(gh2, urs, urt, sCG, sB2, sREM);
  k_gather<<<ROWS * CHUNKS, NTHR, 0, stream>>>(u0s, u0t, tabs, sB1, sB2, gcnt, gkey, gidx);
  k_select<<<ROWS, 1024, 0, stream>>>(gkey, gidx, gcnt, sREM, sT, sIT);
  k_final<<<ROWS * CHUNKS, NTHR, 0, stream>>>(u0s, u0t, tabs, sT, sIT, out);
}

// Round 5
// 377.875 us; speedup vs baseline: 3.2487x; 3.2487x over previous
//
#include <hip/hip_runtime.h>
#include <stdint.h>

#define NTOK 524288
#define ROWS 64
#define CHUNKS 64
#define NTHR 256
#define F4_PER_ROW (NTOK / 4)                 // 131072
#define F4_PER_CHUNK (F4_PER_ROW / CHUNKS)    // 2048
#define F4_PER_THR (F4_PER_CHUNK / NTHR)      // 8
#define GCAP 8192

// ---- workspace layout (bytes) ----
#define OFF_H1   0u
#define OFF_H2   (OFF_H1 + ROWS * 4096u * 4u)          // 1 MiB
#define OFF_B1   (OFF_H2 + ROWS * 4096u * 4u)          // 2 MiB
#define OFF_CG   (OFF_B1 + ROWS * 4u)
#define OFF_B2   (OFF_CG + ROWS * 4u)
#define OFF_REM  (OFF_B2 + ROWS * 4u)
#define OFF_IT   (OFF_REM + ROWS * 4u)
#define OFF_GCNT (OFF_IT + ROWS * 4u)
#define OFF_T    (OFF_GCNT + ROWS * 4u)                // 8-aligned
#define OFF_ZERO_END (OFF_T + ROWS * 8u)
#define OFF_TAB  OFF_ZERO_END                          // 64*112 doubles
#define OFF_GKEY (OFF_TAB + ROWS * 112u * 8u)
#define OFF_GIDX (OFF_GKEY + ROWS * (unsigned)GCAP * 8u)
#define WS_NEED  (OFF_GIDX + ROWS * (unsigned)GCAP * 4u)

__device__ __forceinline__ double clamp64(double x) {
  return fmin(fmax(x, 1.0e-3), 1.0 - 1.0e-3);
}

// ---- K exactly as reference: float32 clamp, float32 multiply, truncate ----
__device__ __forceinline__ unsigned compute_K(float ur) {
  float urf = fminf(fmaxf(ur, 1.0e-3f), 1.0f - 1.0e-3f);
  return (unsigned)(int)(urf * (float)NTOK);
}

// ---- precompute per-row dim factor tables: F = clamp(u)^(1/alpha), f64 ----
__global__ void k_tables(const float* __restrict__ comps, const int* __restrict__ idxp,
                         const float* __restrict__ uvs, const float* __restrict__ uts,
                         const float* __restrict__ uhs, const float* __restrict__ uws,
                         const float* __restrict__ uvt, const float* __restrict__ utt,
                         const float* __restrict__ uht, const float* __restrict__ uwt,
                         double* __restrict__ tabs) {
  int idx = idxp[0];
  double alpha[4];
  for (int d = 0; d < 4; ++d) alpha[d] = (double)comps[idx * 4 + d];
  for (int i = threadIdx.x; i < ROWS * 112; i += blockDim.x) {
    int row = i / 112, j = i % 112;
    int m = row >> 5, b = row & 31;
    int d, jj, dsz;
    if (j < 16)      { d = 0; jj = j;      dsz = 16; }
    else if (j < 48) { d = 1; jj = j - 16; dsz = 32; }
    else if (j < 80) { d = 2; jj = j - 48; dsz = 32; }
    else             { d = 3; jj = j - 80; dsz = 32; }
    const float* u;
    if (m == 0) u = (d == 0) ? uvs : (d == 1) ? uts : (d == 2) ? uhs : uws;
    else        u = (d == 0) ? uvt : (d == 1) ? utt : (d == 2) ? uht : uwt;
    double x = clamp64((double)u[b * dsz + jj]);
    double a = alpha[d];
    double f;
    if (a == 1.0)      f = x;
    else if (a == 2.0) f = sqrt(x);
    else if (a == 4.0) f = sqrt(sqrt(x));
    else               f = pow(x, 1.0 / a);
    tabs[row * 112 + j] = f;
  }
}

// ---- pass 1: 12-bit histogram of key bits [62:51] ----
__global__ void k_hist1(const float* __restrict__ u0s, const float* __restrict__ u0t,
                        const double* __restrict__ tabs, unsigned int* __restrict__ gh1) {
  __shared__ double tb[112];
  __shared__ unsigned int h[4096];
  int row = blockIdx.x / CHUNKS, chunk = blockIdx.x % CHUNKS;
  for (int i = threadIdx.x; i < 112; i += blockDim.x) tb[i] = tabs[row * 112 + i];
  for (int i = threadIdx.x; i < 4096; i += blockDim.x) h[i] = 0;
  __syncthreads();
  int m = row >> 5, b = row & 31;
  const float4* u0 = reinterpret_cast<const float4*>((m ? u0t : u0s) + (size_t)b * NTOK);
  int base = chunk * F4_PER_CHUNK;
  for (int it = 0; it < F4_PER_THR; ++it) {
    int f4 = base + it * NTHR + threadIdx.x;
    float4 x = u0[f4];
    int n0 = f4 * 4;
    int w0 = n0 & 31, hh = (n0 >> 5) & 31, tt = (n0 >> 10) & 31, vv = n0 >> 15;
    double g = tb[vv] * tb[16 + tt] * tb[48 + hh];
    double k0 = clamp64((double)x.x) * (g * tb[80 + w0 + 0]);
    double k1 = clamp64((double)x.y) * (g * tb[80 + w0 + 1]);
    double k2 = clamp64((double)x.z) * (g * tb[80 + w0 + 2]);
    double k3 = clamp64((double)x.w) * (g * tb[80 + w0 + 3]);
    atomicAdd(&h[(unsigned)((unsigned long long)__double_as_longlong(k0) >> 51) & 0xFFFu], 1u);
    atomicAdd(&h[(unsigned)((unsigned long long)__double_as_longlong(k1) >> 51) & 0xFFFu], 1u);
    atomicAdd(&h[(unsigned)((unsigned long long)__double_as_longlong(k2) >> 51) & 0xFFFu], 1u);
    atomicAdd(&h[(unsigned)((unsigned long long)__double_as_longlong(k3) >> 51) & 0xFFFu], 1u);
  }
  __syncthreads();
  for (int i = threadIdx.x; i < 4096; i += blockDim.x) {
    unsigned c = h[i];
    if (c) atomicAdd(&gh1[row * 4096 + i], c);
  }
}

// ---- parallel scan 1: one block per row; find bucket B1 containing K-th largest ----
__global__ __launch_bounds__(256) void k_scan1(const unsigned int* __restrict__ gh1,
                                               const float* __restrict__ urs,
                                               const float* __restrict__ urt,
                                               int* __restrict__ sB1, int* __restrict__ sCG) {
  __shared__ unsigned suf[256];
  __shared__ int best;
  int row = blockIdx.x;
  int t = threadIdx.x;
  const unsigned* h = gh1 + row * 4096;
  unsigned loc[16]; unsigned own = 0;
#pragma unroll
  for (int i = 0; i < 16; ++i) { loc[i] = h[t * 16 + i]; own += loc[i]; }
  suf[t] = own;
  if (t == 0) best = -1;
  __syncthreads();
  for (int off = 1; off < 256; off <<= 1) {
    unsigned add = (t + off < 256) ? suf[t + off] : 0u;
    __syncthreads();
    suf[t] += add;
    __syncthreads();
  }
  int m = row >> 5;
  unsigned K = compute_K(m ? urt[0] : urs[0]);
  unsigned above = suf[t] - own;  // count in buckets strictly above this chunk
  int cand = -1;
  unsigned cum = above;
  for (int i = 15; i >= 0; --i) {
    if (cum + loc[i] >= K) { cand = t * 16 + i; break; }
    cum += loc[i];
  }
  if (cand >= 0) atomicMax(&best, cand);
  __syncthreads();
  int bb = best;
  if (bb >= 0 && (bb >> 4) == t) {
    unsigned cg = above;
    for (int i = 15; i > (bb & 15); --i) cg += loc[i];
    sB1[row] = bb;
    sCG[row] = (int)cg;
  }
}

// ---- pass 2: refine bits [50:39] within bucket B1 ----
__global__ void k_hist2(const float* __restrict__ u0s, const float* __restrict__ u0t,
                        const double* __restrict__ tabs, const int* __restrict__ sB1,
                        unsigned int* __restrict__ gh2) {
  __shared__ double tb[112];
  __shared__ unsigned int h[4096];
  int row = blockIdx.x / CHUNKS, chunk = blockIdx.x % CHUNKS;
  for (int i = threadIdx.x; i < 112; i += blockDim.x) tb[i] = tabs[row * 112 + i];
  for (int i = threadIdx.x; i < 4096; i += blockDim.x) h[i] = 0;
  __syncthreads();
  unsigned b1 = (unsigned)sB1[row];
  int m = row >> 5, b = row & 31;
  const float4* u0 = reinterpret_cast<const float4*>((m ? u0t : u0s) + (size_t)b * NTOK);
  int base = chunk * F4_PER_CHUNK;
  for (int it = 0; it < F4_PER_THR; ++it) {
    int f4 = base + it * NTHR + threadIdx.x;
    float4 x = u0[f4];
    int n0 = f4 * 4;
    int w0 = n0 & 31, hh = (n0 >> 5) & 31, tt = (n0 >> 10) & 31, vv = n0 >> 15;
    double g = tb[vv] * tb[16 + tt] * tb[48 + hh];
    double ks[4];
    ks[0] = clamp64((double)x.x) * (g * tb[80 + w0 + 0]);
    ks[1] = clamp64((double)x.y) * (g * tb[80 + w0 + 1]);
    ks[2] = clamp64((double)x.z) * (g * tb[80 + w0 + 2]);
    ks[3] = clamp64((double)x.w) * (g * tb[80 + w0 + 3]);
#pragma unroll
    for (int c = 0; c < 4; ++c) {
      unsigned long long kb = (unsigned long long)__double_as_longlong(ks[c]);
      if (((unsigned)(kb >> 51) & 0xFFFu) == b1)
        atomicAdd(&h[(unsigned)(kb >> 39) & 0xFFFu], 1u);
    }
  }
  __syncthreads();
  for (int i = threadIdx.x; i < 4096; i += blockDim.x) {
    unsigned c = h[i];
    if (c) atomicAdd(&gh2[row * 4096 + i], c);
  }
}

// ---- parallel scan 2: find bucket B2 + remaining count ----
__global__ __launch_bounds__(256) void k_scan2(const unsigned int* __restrict__ gh2,
                                               const float* __restrict__ urs,
                                               const float* __restrict__ urt,
                                               const int* __restrict__ sCG,
                                               int* __restrict__ sB2, int* __restrict__ sREM) {
  __shared__ unsigned suf[256];
  __shared__ int best;
  int row = blockIdx.x;
  int t = threadIdx.x;
  const unsigned* h = gh2 + row * 4096;
  unsigned loc[16]; unsigned own = 0;
#pragma unroll
  for (int i = 0; i < 16; ++i) { loc[i] = h[t * 16 + i]; own += loc[i]; }
  suf[t] = own;
  if (t == 0) best = -1;
  __syncthreads();
  for (int off = 1; off < 256; off <<= 1) {
    unsigned add = (t + off < 256) ? suf[t + off] : 0u;
    __syncthreads();
    suf[t] += add;
    __syncthreads();
  }
  int m = row >> 5;
  unsigned K = compute_K(m ? urt[0] : urs[0]);
  unsigned K2 = K - (unsigned)sCG[row];   // >= 1
  unsigned above = suf[t] - own;
  int cand = -1;
  unsigned cum = above;
  for (int i = 15; i >= 0; --i) {
    if (cum + loc[i] >= K2) { cand = t * 16 + i; break; }
    cum += loc[i];
  }
  if (cand >= 0) atomicMax(&best, cand);
  __syncthreads();
  int bb = best;
  if (bb >= 0 && (bb >> 4) == t) {
    unsigned a2 = above;
    for (int i = 15; i > (bb & 15); --i) a2 += loc[i];
    sB2[row] = bb;
    sREM[row] = (int)(K2 - a2);
  }
}

// ---- pass 3: gather all elements matching the 24-bit prefix ----
__global__ void k_gather(const float* __restrict__ u0s, const float* __restrict__ u0t,
                         const double* __restrict__ tabs,
                         const int* __restrict__ sB1, const int* __restrict__ sB2,
                         unsigned int* __restrict__ gcnt,
                         unsigned long long* __restrict__ gkey, unsigned int* __restrict__ gidx) {
  __shared__ double tb[112];
  int row = blockIdx.x / CHUNKS, chunk = blockIdx.x % CHUNKS;
  for (int i = threadIdx.x; i < 112; i += blockDim.x) tb[i] = tabs[row * 112 + i];
  __syncthreads();
  unsigned pref = ((unsigned)sB1[row] << 12) | (unsigned)sB2[row];
  int m = row >> 5, b = row & 31;
  const float4* u0 = reinterpret_cast<const float4*>((m ? u0t : u0s) + (size_t)b * NTOK);
  int base = chunk * F4_PER_CHUNK;
  for (int it = 0; it < F4_PER_THR; ++it) {
    int f4 = base + it * NTHR + threadIdx.x;
    float4 x = u0[f4];
    int n0 = f4 * 4;
    int w0 = n0 & 31, hh = (n0 >> 5) & 31, tt = (n0 >> 10) & 31, vv = n0 >> 15;
    double g = tb[vv] * tb[16 + tt] * tb[48 + hh];
    double ks[4];
    ks[0] = clamp64((double)x.x) * (g * tb[80 + w0 + 0]);
    ks[1] = clamp64((double)x.y) * (g * tb[80 + w0 + 1]);
    ks[2] = clamp64((double)x.z) * (g * tb[80 + w0 + 2]);
    ks[3] = clamp64((double)x.w) * (g * tb[80 + w0 + 3]);
#pragma unroll
    for (int c = 0; c < 4; ++c) {
      unsigned long long kb = (unsigned long long)__double_as_longlong(ks[c]);
      if (((unsigned)(kb >> 39) & 0xFFFFFFu) == pref) {
        unsigned pos = atomicAdd(&gcnt[row], 1u);
        if (pos < GCAP) {
          gkey[(size_t)row * GCAP + pos] = kb;
          gidx[(size_t)row * GCAP + pos] = (unsigned)(n0 + c);
        }
      }
    }
  }
}

// ---- pass 4: one block per row, bitonic sort of the (small) gathered set ----
__global__ __launch_bounds__(1024) void k_select(const unsigned long long* __restrict__ gkey,
                                                 const unsigned int* __restrict__ gidx,
                                                 const unsigned int* __restrict__ gcnt,
                                                 const int* __restrict__ sREM,
                                                 unsigned long long* __restrict__ sT,
                                                 int* __restrict__ sIT) {
  __shared__ unsigned long long k[GCAP];
  __shared__ unsigned int ix[GCAP];
  int row = blockIdx.x;
  unsigned n_r = gcnt[row];
  if (n_r > GCAP) n_r = GCAP;
  // sort size: next pow2 >= n_r (min 2)
  unsigned n2 = 2;
  while (n2 < n_r) n2 <<= 1;
  for (int i = threadIdx.x; i < (int)n2; i += blockDim.x) {
    if ((unsigned)i < n_r) { k[i] = gkey[(size_t)row * GCAP + i]; ix[i] = gidx[(size_t)row * GCAP + i]; }
    else                   { k[i] = 0ULL; ix[i] = 0xFFFFFFFFu; }
  }
  __syncthreads();
  for (unsigned kk = 2; kk <= n2; kk <<= 1) {
    for (unsigned j = kk >> 1; j > 0; j >>= 1) {
      for (int i = threadIdx.x; i < (int)n2; i += blockDim.x) {
        int pj = i ^ (int)j;
        if (pj > i) {
          unsigned long long k1 = k[i], k2 = k[pj];
          unsigned i1 = ix[i], i2 = ix[pj];
          bool bef = (k1 > k2) || (k1 == k2 && i1 < i2);  // i's element should precede
          bool dirAsc = ((i & (int)kk) == 0);
          if (bef != dirAsc) { k[i] = k2; k[pj] = k1; ix[i] = i2; ix[pj] = i1; }
        }
      }
      __syncthreads();
    }
  }
  if (threadIdx.x == 0) {
    int rem = sREM[row];
    if (rem < 1) rem = 1;
    if ((unsigned)rem > n_r) rem = (int)n_r;
    sT[row] = k[rem - 1];
    sIT[row] = (int)ix[rem - 1];
  }
}

// ---- pass 5: write masks as int32 0/1 ----
__global__ void k_final(const float* __restrict__ u0s, const float* __restrict__ u0t,
                        const double* __restrict__ tabs,
                        const unsigned long long* __restrict__ sT, const int* __restrict__ sIT,
                        int* __restrict__ out) {
  __shared__ double tb[112];
  int row = blockIdx.x / CHUNKS, chunk = blockIdx.x % CHUNKS;
  for (int i = threadIdx.x; i < 112; i += blockDim.x) tb[i] = tabs[row * 112 + i];
  __syncthreads();
  unsigned long long T = sT[row];
  int IT = sIT[row];
  int m = row >> 5, b = row & 31;
  const float4* u0 = reinterpret_cast<const float4*>((m ? u0t : u0s) + (size_t)b * NTOK);
  int4* o = reinterpret_cast<int4*>(out + (size_t)row * NTOK);
  int base = chunk * F4_PER_CHUNK;
  for (int it = 0; it < F4_PER_THR; ++it) {
    int f4 = base + it * NTHR + threadIdx.x;
    float4 x = u0[f4];
    int n0 = f4 * 4;
    int w0 = n0 & 31, hh = (n0 >> 5) & 31, tt = (n0 >> 10) & 31, vv = n0 >> 15;
    double g = tb[vv] * tb[16 + tt] * tb[48 + hh];
    unsigned long long kb0 = (unsigned long long)__double_as_longlong(clamp64((double)x.x) * (g * tb[80 + w0 + 0]));
    unsigned long long kb1 = (unsigned long long)__double_as_longlong(clamp64((double)x.y) * (g * tb[80 + w0 + 1]));
    unsigned long long kb2 = (unsigned long long)__double_as_longlong(clamp64((double)x.z) * (g * tb[80 + w0 + 2]));
    unsigned long long kb3 = (unsigned long long)__double_as_longlong(clamp64((double)x.w) * (g * tb[80 + w0 + 3]));
    int4 r;
    r.x = (kb0 > T || (kb0 == T && (n0 + 0) <= IT)) ? 1 : 0;
    r.y = (kb1 > T || (kb1 == T && (n0 + 1) <= IT)) ? 1 : 0;
    r.z = (kb2 > T || (kb2 == T && (n0 + 2) <= IT)) ? 1 : 0;
    r.w = (kb3 > T || (kb3 == T && (n0 + 3) <= IT)) ? 1 : 0;
    o[f4] = r;
  }
}

extern "C" void kernel_launch(void* const* d_in, const int* in_sizes, int n_in,
                              void* d_out, int out_size, void* d_ws, size_t ws_size,
                              hipStream_t stream) {
  const float* comps = (const float*)d_in[0];
  const float* urs   = (const float*)d_in[1];
  const float* urt   = (const float*)d_in[2];
  const float* u0s   = (const float*)d_in[3];
  const float* u0t   = (const float*)d_in[4];
  const float* uvs   = (const float*)d_in[5];
  const float* uts   = (const float*)d_in[6];
  const float* uhs   = (const float*)d_in[7];
  const float* uws   = (const float*)d_in[8];
  const float* uvt   = (const float*)d_in[9];
  const float* utt   = (const float*)d_in[10];
  const float* uht   = (const float*)d_in[11];
  const float* uwt   = (const float*)d_in[12];
  const int*   idxp  = (const int*)d_in[13];
  int* out = (int*)d_out;

  char* ws = (char*)d_ws;
  unsigned int*       gh1  = (unsigned int*)(ws + OFF_H1);
  unsigned int*       gh2  = (unsigned int*)(ws + OFF_H2);
  int*                sB1  = (int*)(ws + OFF_B1);
  int*                sCG  = (int*)(ws + OFF_CG);
  int*                sB2  = (int*)(ws + OFF_B2);
  int*                sREM = (int*)(ws + OFF_REM);
  int*                sIT  = (int*)(ws + OFF_IT);
  unsigned int*       gcnt = (unsigned int*)(ws + OFF_GCNT);
  unsigned long long* sT   = (unsigned long long*)(ws + OFF_T);
  double*             tabs = (double*)(ws + OFF_TAB);
  unsigned long long* gkey = (unsigned long long*)(ws + OFF_GKEY);
  unsigned int*       gidx = (unsigned int*)(ws + OFF_GIDX);

  // zero hists + state + counters (ws is poisoned 0xAA before every call)
  hipMemsetAsync(d_ws, 0, OFF_ZERO_END, stream);

  k_tables<<<1, 256, 0, stream>>>(comps, idxp, uvs, uts, uhs, uws, uvt, utt, uht, uwt, tabs);
  k_hist1<<<ROWS * CHUNKS, NTHR, 0, stream>>>(u0s, u0t, tabs, gh1);
  k_scan1<<<ROWS, 256, 0, stream>>>(gh1, urs, urt, sB1, sCG);
  k_hist2<<<ROWS * CHUNKS, NTHR, 0, stream>>>(u0s, u0t, tabs, sB1, gh2);
  k_scan2<<<ROWS, 256, 0, stream>>>(gh2, urs, urt, sCG, sB2, sREM);
  k_gather<<<ROWS * CHUNKS, NTHR, 0, stream>>>(u0s, u0t, tabs, sB1, sB2, gcnt, gkey, gidx);
  k_select<<<ROWS, 1024, 0, stream>>>(gkey, gidx, gcnt, sREM, sT, sIT);
  k_final<<<ROWS * CHUNKS, NTHR, 0, stream>>>(u0s, u0t, tabs, sT, sIT, out);
}